// Round 4
// baseline (3403.341 us; speedup 1.0000x reference)
//
#include <hip/hip_runtime.h>
#include <hip/hip_bf16.h>
#include <math.h>

#define DMODEL 4096
#define NROWS  8192          // B*N = 4*2048
#define DFF    5461
#define CHUNK  512
#define NCHUNK 16
#define LNEPS  1e-5f
#define NSHADOW 4            // shadow copies of ctv/ntv/htv to cut atomic contention

// split-fp16 MFMA GEMM params
#define GBM 128
#define GBN 128
#define GBK 32
#define LOSCALE 2048.0f      // 2^11
#define LOINV   4.8828125e-4f // 2^-11

typedef _Float16 h8 __attribute__((ext_vector_type(8)));
typedef _Float16 h4 __attribute__((ext_vector_type(4)));
typedef float floatx4 __attribute__((ext_vector_type(4)));

__device__ inline unsigned short f2bf(float f) {
    unsigned int x = __builtin_bit_cast(unsigned int, f);
    unsigned int r = x + 0x7FFFu + ((x >> 16) & 1u);   // RNE
    return (unsigned short)(r >> 16);
}
__device__ inline float bf2f(unsigned short u) {
    return __builtin_bit_cast(float, ((unsigned int)u) << 16);
}

#define GLL(gp, lp) __builtin_amdgcn_global_load_lds( \
    (const __attribute__((address_space(1))) void*)(gp), \
    (__attribute__((address_space(3))) void*)(lp), 16, 0, 0)

// ---------------- prep: silu(x) fp32 -> fp16 hi/lo split ----------------
__global__ __launch_bounds__(256) void silu_split_k(const float* __restrict__ x,
                                                    _Float16* __restrict__ xh,
                                                    _Float16* __restrict__ xl) {
    size_t i = (size_t)blockIdx.x * 256 + threadIdx.x;   // float4 index
    float4 v = ((const float4*)x)[i];
    float s[4];
    s[0] = v.x / (1.f + expf(-v.x));
    s[1] = v.y / (1.f + expf(-v.y));
    s[2] = v.z / (1.f + expf(-v.z));
    s[3] = v.w / (1.f + expf(-v.w));
    h4 hi, lo;
#pragma unroll
    for (int j = 0; j < 4; ++j) {
        _Float16 h = (_Float16)s[j];
        hi[j] = h;
        lo[j] = (_Float16)((s[j] - (float)h) * LOSCALE);
    }
    ((h4*)xh)[i] = hi;
    ((h4*)xl)[i] = lo;
}

// ---------------- prep: W_gates fp32 -> fp16 hi/lo split ----------------
__global__ __launch_bounds__(256) void wsplit_k(const float* __restrict__ Wg,
                                                _Float16* __restrict__ wh,
                                                _Float16* __restrict__ wl) {
    size_t i = (size_t)blockIdx.x * 256 + threadIdx.x;
    float4 v = ((const float4*)Wg)[i];
    float s[4] = {v.x, v.y, v.z, v.w};
    h4 hi, lo;
#pragma unroll
    for (int j = 0; j < 4; ++j) {
        _Float16 h = (_Float16)s[j];
        hi[j] = h;
        lo[j] = (_Float16)((s[j] - (float)h) * LOSCALE);
    }
    ((h4*)wh)[i] = hi;
    ((h4*)wl)[i] = lo;
}

// ---------------- block-diagonal gate GEMM, split-fp16 MFMA (~fp32 precision) ----------------
// pre[g, row, kb*1024 + o] = sum_i silu(x)[row, kb*1024+i] * Wg[g,kb,o,i]
// grid: x = 1024/GBN (=8), y = CHUNK/GBM (=4), z = 16 (g*4+kb)
__global__ __launch_bounds__(256, 2) void gemm_split_k(
    const _Float16* __restrict__ xh, const _Float16* __restrict__ xl,
    const _Float16* __restrict__ wh, const _Float16* __restrict__ wl,
    float* __restrict__ pre, int row0)
{
    __shared__ __align__(16) _Float16 Ah[GBM * GBK];   // 8 KB each, 32 KB total
    __shared__ __align__(16) _Float16 Al[GBM * GBK];
    __shared__ __align__(16) _Float16 Bh[GBN * GBK];
    __shared__ __align__(16) _Float16 Bl[GBN * GBK];

    const int gz = blockIdx.z;
    const int kb = gz & 3, g = gz >> 2;
    const int tM = blockIdx.y, tN = blockIdx.x;
    const int t = threadIdx.x;
    const int w = t >> 6, l = t & 63;
    const int lane15 = l & 15, quad = l >> 4;
    const int wm = w >> 1, wn = w & 1;

    const size_t Aoff = (size_t)(row0 + tM * GBM) * DMODEL + kb * 1024;
    const size_t Boff = (size_t)gz * (1024 * 1024) + (size_t)(tN * GBN) * 1024;

    floatx4 acc_h[4][4] = {};
    floatx4 acc_x[4][4] = {};

    for (int kt = 0; kt < 1024; kt += GBK) {
        const _Float16* ahs = xh + Aoff + kt;
        const _Float16* als = xl + Aoff + kt;
        const _Float16* bhs = wh + Boff + kt;
        const _Float16* bls = wl + Boff + kt;
#pragma unroll
        for (int it = 0; it < 2; ++it) {
            const int chunk = it * 256 + t;       // 0..511 16B-chunks per tile
            const int r = chunk >> 2;             // tile row 0..127
            const int c = (chunk & 3) * 8;        // k-offset in halfs
            const int lo = (it * 256 + w * 64) * 8;  // wave-uniform LDS base (elements)
            const size_t ga = (size_t)r * DMODEL + c;
            const size_t gb = (size_t)r * 1024 + c;
            GLL(ahs + ga, Ah + lo);
            GLL(als + ga, Al + lo);
            GLL(bhs + gb, Bh + lo);
            GLL(bls + gb, Bl + lo);
        }
        __syncthreads();

        h8 af[4], alf[4], bf[4], blf[4];
#pragma unroll
        for (int mi = 0; mi < 4; ++mi) {
            const int ro = (wm * 64 + mi * 16 + lane15) * GBK + quad * 8;
            af[mi]  = *(const h8*)&Ah[ro];
            alf[mi] = *(const h8*)&Al[ro];
        }
#pragma unroll
        for (int ni = 0; ni < 4; ++ni) {
            const int ro = (wn * 64 + ni * 16 + lane15) * GBK + quad * 8;
            bf[ni]  = *(const h8*)&Bh[ro];
            blf[ni] = *(const h8*)&Bl[ro];
        }
#pragma unroll
        for (int mi = 0; mi < 4; ++mi)
#pragma unroll
            for (int ni = 0; ni < 4; ++ni) {
                acc_h[mi][ni] = __builtin_amdgcn_mfma_f32_16x16x32_f16(
                    af[mi], bf[ni], acc_h[mi][ni], 0, 0, 0);
                acc_x[mi][ni] = __builtin_amdgcn_mfma_f32_16x16x32_f16(
                    af[mi], blf[ni], acc_x[mi][ni], 0, 0, 0);
                acc_x[mi][ni] = __builtin_amdgcn_mfma_f32_16x16x32_f16(
                    alf[mi], bf[ni], acc_x[mi][ni], 0, 0, 0);
            }
        __syncthreads();
    }

#pragma unroll
    for (int mi = 0; mi < 4; ++mi) {
#pragma unroll
        for (int r = 0; r < 4; ++r) {
            const int rowl = tM * GBM + wm * 64 + mi * 16 + quad * 4 + r;
            float* dst = pre + ((size_t)g * CHUNK + rowl) * DMODEL
                         + kb * 1024 + tN * GBN + wn * 64 + lane15;
#pragma unroll
            for (int ni = 0; ni < 4; ++ni)
                dst[ni * 16] = acc_h[mi][ni][r] + acc_x[mi][ni][r] * LOINV;
        }
    }
}

// ---------------- block reduction, 1024 threads = 16 waves ----------------
template <int N>
__device__ inline void block_reduce16(float* s, float* red) {
    const int t = threadIdx.x, w = t >> 6, l = t & 63;
#pragma unroll
    for (int i = 0; i < N; ++i) {
        float v = s[i];
#pragma unroll
        for (int off = 32; off > 0; off >>= 1) v += __shfl_xor(v, off, 64);
        if (l == 0) red[w * N + i] = v;
    }
    __syncthreads();
#pragma unroll
    for (int i = 0; i < N; ++i) {
        float acc = 0.f;
#pragma unroll
        for (int ww = 0; ww < 16; ++ww) acc += red[ww * N + i];
        s[i] = acc;
    }
    __syncthreads();   // red reused by next call
}

// ---------------- block reduction, 256 threads = 4 waves ----------------
template <int N>
__device__ inline void block_reduce(float* s, float* red) {
    const int t = threadIdx.x, w = t >> 6, l = t & 63;
#pragma unroll
    for (int i = 0; i < N; ++i) {
        float v = s[i];
#pragma unroll
        for (int off = 32; off > 0; off >>= 1) v += __shfl_xor(v, off, 64);
        if (l == 0) red[w * N + i] = v;
    }
    __syncthreads();
#pragma unroll
    for (int i = 0; i < N; ++i)
        s[i] = red[0 * N + i] + red[1 * N + i] + red[2 * N + i] + red[3 * N + i];
    __syncthreads();
}

// ---------------- fused LN + gates + ct/nt accumulation: ONE ROW PER 1024-THREAD BLOCK ----
// All 4x4 gate values held in registers; three phases without re-reading pre.
__global__ __launch_bounds__(1024) void lnpass_k(
    const float* __restrict__ pre, const float* __restrict__ bg,
    const float* __restrict__ lng, const float* __restrict__ lnb,
    unsigned short* __restrict__ obuf,
    float* __restrict__ ctv, float* __restrict__ ntv, int row0)
{
    __shared__ float red[16 * 8];
    const int t = threadIdx.x;            // 0..1023; owns d = 4t..4t+3
    const int rl = blockIdx.x;            // row within chunk
    const float n1 = 1.f / DMODEL;

    // load row (4 gates x 4 elements) + bias into registers
    float v[4][4];
#pragma unroll
    for (int g = 0; g < 4; ++g) {
        float4 pv = ((const float4*)(pre + ((size_t)g * CHUNK + rl) * DMODEL))[t];
        float4 bv = ((const float4*)bg)[g * (DMODEL / 4) + t];
        v[g][0] = pv.x + bv.x; v[g][1] = pv.y + bv.y;
        v[g][2] = pv.z + bv.z; v[g][3] = pv.w + bv.w;
    }

    // phase 1: per-gate row stats
    float s[8];
#pragma unroll
    for (int g = 0; g < 4; ++g) {
        s[2 * g]     = v[g][0] + v[g][1] + v[g][2] + v[g][3];
        s[2 * g + 1] = v[g][0] * v[g][0] + v[g][1] * v[g][1]
                     + v[g][2] * v[g][2] + v[g][3] * v[g][3];
    }
    block_reduce16<8>(s, red);
    const float mu0 = s[0] * n1, rs0 = rsqrtf(s[1] * n1 - mu0 * mu0 + LNEPS);
    const float mu1 = s[2] * n1, rs1 = rsqrtf(s[3] * n1 - mu1 * mu1 + LNEPS);
    const float mu2 = s[4] * n1, rs2 = rsqrtf(s[5] * n1 - mu2 * mu2 + LNEPS);
    const float mu3 = s[6] * n1, rs3 = rsqrtf(s[7] * n1 - mu3 * mu3 + LNEPS);

    // phase 2: i, z, c = i*z and their row stats
    float4 g0 = ((const float4*)lng)[0 * (DMODEL / 4) + t], b0 = ((const float4*)lnb)[0 * (DMODEL / 4) + t];
    float4 g1 = ((const float4*)lng)[1 * (DMODEL / 4) + t], b1 = ((const float4*)lnb)[1 * (DMODEL / 4) + t];
    float4 g3 = ((const float4*)lng)[3 * (DMODEL / 4) + t], b3 = ((const float4*)lnb)[3 * (DMODEL / 4) + t];
    const float* g0p = (const float*)&g0; const float* b0p = (const float*)&b0;
    const float* g1p = (const float*)&g1; const float* b1p = (const float*)&b1;
    const float* g3p = (const float*)&g3; const float* b3p = (const float*)&b3;

    float cv[4], iv[4];
    float s2[4] = {};
#pragma unroll
    for (int e = 0; e < 4; ++e) {
        float li = (v[0][e] - mu0) * rs0 * g0p[e] + b0p[e];
        float lf = (v[1][e] - mu1) * rs1 * g1p[e] + b1p[e];
        float ii = expf(fminf(li - lf, 0.f));     // i = exp(log_i - max(log_i, log_f))
        float zz = tanhf((v[3][e] - mu3) * rs3 * g3p[e] + b3p[e]);
        float cc = ii * zz;
        cv[e] = cc; iv[e] = ii;
        s2[0] += cc; s2[1] += cc * cc;
        s2[2] += ii; s2[3] += ii * ii;
    }
    block_reduce16<4>(s2, red);
    const float cmu = s2[0] * n1, crs = rsqrtf(s2[1] * n1 - cmu * cmu + LNEPS);
    const float nmu = s2[2] * n1, nrs = rsqrtf(s2[3] * n1 - nmu * nmu + LNEPS);

    // phase 3: LN4/LN5 contributions + o gate (bf16) from registers
    float4 g4 = ((const float4*)lng)[4 * (DMODEL / 4) + t], b4 = ((const float4*)lnb)[4 * (DMODEL / 4) + t];
    float4 g5 = ((const float4*)lng)[5 * (DMODEL / 4) + t], b5 = ((const float4*)lnb)[5 * (DMODEL / 4) + t];
    float4 g2 = ((const float4*)lng)[2 * (DMODEL / 4) + t], b2 = ((const float4*)lnb)[2 * (DMODEL / 4) + t];
    const float* g4p = (const float*)&g4; const float* b4p = (const float*)&b4;
    const float* g5p = (const float*)&g5; const float* b5p = (const float*)&b5;
    const float* g2p = (const float*)&g2; const float* b2p = (const float*)&b2;

    float cta[4], nta[4];
    unsigned short ob[4];
#pragma unroll
    for (int e = 0; e < 4; ++e) {
        cta[e] = (cv[e] - cmu) * crs * g4p[e] + b4p[e];
        nta[e] = (iv[e] - nmu) * nrs * g5p[e] + b5p[e];
        float ov = (v[2][e] - mu2) * rs2 * g2p[e] + b2p[e];
        ov = 1.f / (1.f + expf(-ov));
        ob[e] = f2bf(ov);
    }
    ushort4 obv = make_ushort4(ob[0], ob[1], ob[2], ob[3]);
    ((ushort4*)(obuf + (size_t)(row0 + rl) * DMODEL))[t] = obv;

    const int sh = (blockIdx.x & (NSHADOW - 1)) * DMODEL + 4 * t;
#pragma unroll
    for (int e = 0; e < 4; ++e) {
        atomicAdd(&ctv[sh + e], cta[e]);
        atomicAdd(&ntv[sh + e], nta[e]);
    }
}

// ---------------- ht = o * (ctv/ntv), LN6 per row, accumulate row-mean ----------------
#define HROWS 4
__global__ __launch_bounds__(1024) void htpass_k(
    const unsigned short* __restrict__ obuf,
    const float* __restrict__ ctv, const float* __restrict__ ntv,
    const float* __restrict__ lng, const float* __restrict__ lnb,
    float* __restrict__ htv)
{
    __shared__ float red[16 * 2];
    const int t = threadIdx.x;
    const float n1 = 1.f / DMODEL;

    float r[4];
    {
        float4 c0 = ((const float4*)ctv)[0 * (DMODEL / 4) + t];
        float4 c1 = ((const float4*)ctv)[1 * (DMODEL / 4) + t];
        float4 c2 = ((const float4*)ctv)[2 * (DMODEL / 4) + t];
        float4 c3 = ((const float4*)ctv)[3 * (DMODEL / 4) + t];
        float4 d0 = ((const float4*)ntv)[0 * (DMODEL / 4) + t];
        float4 d1 = ((const float4*)ntv)[1 * (DMODEL / 4) + t];
        float4 d2 = ((const float4*)ntv)[2 * (DMODEL / 4) + t];
        float4 d3 = ((const float4*)ntv)[3 * (DMODEL / 4) + t];
        r[0] = (c0.x + c1.x + c2.x + c3.x) / (d0.x + d1.x + d2.x + d3.x);
        r[1] = (c0.y + c1.y + c2.y + c3.y) / (d0.y + d1.y + d2.y + d3.y);
        r[2] = (c0.z + c1.z + c2.z + c3.z) / (d0.z + d1.z + d2.z + d3.z);
        r[3] = (c0.w + c1.w + c2.w + c3.w) / (d0.w + d1.w + d2.w + d3.w);
    }
    float4 g6 = ((const float4*)lng)[6 * (DMODEL / 4) + t];
    float4 b6 = ((const float4*)lnb)[6 * (DMODEL / 4) + t];
    const float* g6p = (const float*)&g6; const float* b6p = (const float*)&b6;

    float hacc[4] = {};
    for (int rr = 0; rr < HROWS; ++rr) {
        const int row = blockIdx.x * HROWS + rr;
        ushort4 ov = ((const ushort4*)(obuf + (size_t)row * DMODEL))[t];
        float h[4];
        h[0] = bf2f(ov.x) * r[0]; h[1] = bf2f(ov.y) * r[1];
        h[2] = bf2f(ov.z) * r[2]; h[3] = bf2f(ov.w) * r[3];
        float s[2];
        s[0] = h[0] + h[1] + h[2] + h[3];
        s[1] = h[0] * h[0] + h[1] * h[1] + h[2] * h[2] + h[3] * h[3];
        block_reduce16<2>(s, red);
        const float mu = s[0] * n1, rsv = rsqrtf(s[1] * n1 - mu * mu + LNEPS);
#pragma unroll
        for (int e = 0; e < 4; ++e)
            hacc[e] += (h[e] - mu) * rsv * g6p[e] + b6p[e];
    }
    const int sh = (blockIdx.x & (NSHADOW - 1)) * DMODEL + 4 * t;
#pragma unroll
    for (int e = 0; e < 4; ++e) atomicAdd(&htv[sh + e], hacc[e]);
}

// ---------------- slstm_out = LN7(mean ht) ----------------
__global__ __launch_bounds__(256) void finalvec_k(
    const float* __restrict__ htv, const float* __restrict__ lng,
    const float* __restrict__ lnb, float* __restrict__ sout)
{
    __shared__ float red[8];
    const int t = threadIdx.x;
    const float n1 = 1.f / DMODEL;
    float v[16]; float s[2] = {};
    for (int j = 0; j < 16; ++j) {
        const int d = t + 256 * j;
        float hv = htv[d] + htv[DMODEL + d] + htv[2 * DMODEL + d] + htv[3 * DMODEL + d];
        v[j] = hv * (1.f / (float)NROWS);
        s[0] += v[j]; s[1] += v[j] * v[j];
    }
    block_reduce<2>(s, red);
    const float mu = s[0] * n1, rs = rsqrtf(s[1] * n1 - mu * mu + LNEPS);
    for (int j = 0; j < 16; ++j) {
        const int d = t + 256 * j;
        sout[d] = (v[j] - mu) * rs * lng[7 * DMODEL + d] + lnb[7 * DMODEL + d];
    }
}

// ---------------- left/right GEMV + exact gelu, one wave per output f ----------------
__global__ __launch_bounds__(256) void ffn1_k(
    const float* __restrict__ sout,
    const float* __restrict__ Wl, const float* __restrict__ bl,
    const float* __restrict__ Wr, const float* __restrict__ br,
    float* __restrict__ u)
{
    const int t = threadIdx.x, w = t >> 6, l = t & 63;
    const int f = blockIdx.x * 4 + w;
    if (f >= DFF) return;
    const float4* wl4 = (const float4*)(Wl + (size_t)f * DMODEL);
    const float4* wr4 = (const float4*)(Wr + (size_t)f * DMODEL);
    const float4* s4 = (const float4*)sout;
    float a = 0.f, b = 0.f;
#pragma unroll
    for (int jj = 0; jj < 16; ++jj) {
        const int i4 = l + 64 * jj;
        float4 sv = s4[i4], av = wl4[i4], bv = wr4[i4];
        a += sv.x * av.x + sv.y * av.y + sv.z * av.z + sv.w * av.w;
        b += sv.x * bv.x + sv.y * bv.y + sv.z * bv.z + sv.w * bv.w;
    }
#pragma unroll
    for (int off = 32; off > 0; off >>= 1) {
        a += __shfl_xor(a, off, 64);
        b += __shfl_xor(b, off, 64);
    }
    if (l == 0) {
        float lv = a + bl[f];
        float rv = b + br[f];
        float g = 0.5f * rv * (1.f + erff(rv * 0.70710678118654752f));  // exact gelu
        u[f] = lv * g;
    }
}

// ---------------- LN over DFF ----------------
__global__ __launch_bounds__(256) void lnout_k(
    const float* __restrict__ u, const float* __restrict__ g,
    const float* __restrict__ b, float* __restrict__ y)
{
    __shared__ float red[8];
    const int t = threadIdx.x;
    float s[2] = {};
    for (int d = t; d < DFF; d += 256) { float v = u[d]; s[0] += v; s[1] += v * v; }
    block_reduce<2>(s, red);
    const float n1 = 1.f / (float)DFF;
    const float mu = s[0] * n1, rs = rsqrtf(s[1] * n1 - mu * mu + LNEPS);
    for (int d = t; d < DFF; d += 256) y[d] = (u[d] - mu) * rs * g[d] + b[d];
}

// ---------------- proj GEMV, one wave per output d ----------------
__global__ __launch_bounds__(256) void ffn2_k(
    const float* __restrict__ y, const float* __restrict__ Wp,
    const float* __restrict__ bp, float* __restrict__ out)
{
    const int t = threadIdx.x, w = t >> 6, l = t & 63;
    const int d = blockIdx.x * 4 + w;
    const float* row = Wp + (size_t)d * DFF;
    float s = 0.f;
    for (int j = l; j < DFF; j += 64) s += row[j] * y[j];
#pragma unroll
    for (int off = 32; off > 0; off >>= 1) s += __shfl_xor(s, off, 64);
    if (l == 0) out[d] = s + bp[d];
}

extern "C" void kernel_launch(void* const* d_in, const int* in_sizes, int n_in,
                              void* d_out, int out_size, void* d_ws, size_t ws_size,
                              hipStream_t stream)
{
    const float* x   = (const float*)d_in[0];
    const float* Wg  = (const float*)d_in[1];
    const float* bg  = (const float*)d_in[2];
    // d_in[3] = Wr_gates: provably unused (ht_1 == 0)
    const float* lng = (const float*)d_in[4];
    const float* lnb = (const float*)d_in[5];
    const float* log_ = (const float*)d_in[6];
    const float* lob  = (const float*)d_in[7];
    const float* Wl  = (const float*)d_in[8];
    const float* bl  = (const float*)d_in[9];
    const float* Wr  = (const float*)d_in[10];
    const float* br  = (const float*)d_in[11];
    const float* Wp  = (const float*)d_in[12];
    const float* bp  = (const float*)d_in[13];
    float* out = (float*)d_out;

    char* ws = (char*)d_ws;
    size_t off = 0;
    _Float16* xh = (_Float16*)(ws + off); off += (size_t)NROWS * DMODEL * 2;        // 64 MB
    _Float16* xl = (_Float16*)(ws + off); off += (size_t)NROWS * DMODEL * 2;        // 64 MB
    _Float16* whp = (_Float16*)(ws + off); off += (size_t)16 * 1024 * 1024 * 2;     // 32 MB
    _Float16* wlp = (_Float16*)(ws + off); off += (size_t)16 * 1024 * 1024 * 2;     // 32 MB
    float* pre  = (float*)(ws + off); off += (size_t)4 * CHUNK * DMODEL * 4;        // 32 MB
    float* ctv  = (float*)(ws + off); off += NSHADOW * DMODEL * 4;
    float* ntv  = (float*)(ws + off); off += NSHADOW * DMODEL * 4;
    float* htv  = (float*)(ws + off); off += NSHADOW * DMODEL * 4;
    float* sout = (float*)(ws + off); off += DMODEL * 4;
    float* u    = (float*)(ws + off); off += DFF * 4;
    float* y    = (float*)(ws + off); off += DFF * 4;

    // obuf aliases xl: chunk c's xl rows are last read by gemm(c), and obuf rows
    // [c*CHUNK, (c+1)*CHUNK) are written only by lnpass(c), which is stream-ordered
    // after gemm(c). htpass reads obuf after all chunks. Total ws stays ~224 MB.
    unsigned short* obuf = (unsigned short*)xl;

    // zero the shadow accumulators (ctv, ntv, htv contiguous: 3 * NSHADOW * DMODEL)
    hipMemsetAsync(ctv, 0, 3 * NSHADOW * DMODEL * 4, stream);

    silu_split_k<<<(NROWS * DMODEL) / 1024, 256, 0, stream>>>(x, xh, xl);
    wsplit_k<<<(16 * 1024 * 1024) / 1024, 256, 0, stream>>>(Wg, whp, wlp);

    for (int c = 0; c < NCHUNK; ++c) {
        const int row0 = c * CHUNK;
        dim3 grid(1024 / GBN, CHUNK / GBM, 16);
        gemm_split_k<<<grid, 256, 0, stream>>>(xh, xl, whp, wlp, pre, row0);
        lnpass_k<<<CHUNK, 1024, 0, stream>>>(pre, bg, lng, lnb, obuf, ctv, ntv, row0);
    }

    htpass_k<<<NROWS / HROWS, 1024, 0, stream>>>(obuf, ctv, ntv, lng, lnb, htv);
    finalvec_k<<<1, 256, 0, stream>>>(htv, lng, lnb, sout);
    ffn1_k<<<(DFF + 3) / 4, 256, 0, stream>>>(sout, Wl, bl, Wr, br, u);
    lnout_k<<<1, 256, 0, stream>>>(u, log_, lob, y);
    ffn2_k<<<DMODEL / 4, 256, 0, stream>>>(y, Wp, bp, out);

    (void)in_sizes; (void)n_in; (void)out_size; (void)ws_size;
}